// Round 13
// baseline (286.321 us; speedup 1.0000x reference)
//
#include <hip/hip_runtime.h>
#include <stdint.h>

#define S_LEN   4096
#define D_MODEL 1024
#define N_HEADS 16
#define HEAD_DIM 64
#define LDP 72          // padded stride for Ps only (ds_write path, padding legal)

typedef __attribute__((ext_vector_type(8))) short bf16x8;   // 8 bf16 in 4 VGPRs
typedef __attribute__((ext_vector_type(4))) float f32x4;
typedef __attribute__((ext_vector_type(4))) unsigned short u16x4;
typedef unsigned short ushort_t;

#define LOG2E 1.44269504088896340736f
// Fixed softmax shift: scores in log2 units are ~N(0,1.44); shift of 20 gives
// huge margin and cancels exactly in sum(p*v)/sum(p).
// madd fold: (1-m)*(-10000*log2e) - 20 = fmaf(m, 14426.9504, -14446.9504)

__device__ __forceinline__ ushort_t f2bf(float f) {          // RNE (epilogues)
    union { float f; uint32_t u; } v; v.f = f;
    uint32_t u = v.u;
    return (ushort_t)((u + 0x7fffu + ((u >> 16) & 1u)) >> 16);
}
__device__ __forceinline__ ushort_t f2bf_fast(float f) {     // round-half-up
    union { float f; uint32_t u; } v; v.f = f;
    return (ushort_t)((v.u + 0x8000u) >> 16);
}
__device__ __forceinline__ float ex2(float x) {
#if __has_builtin(__builtin_amdgcn_exp2f)
    return __builtin_amdgcn_exp2f(x);   // single v_exp_f32
#else
    return exp2f(x);
#endif
}
__device__ __forceinline__ bf16x8 cvt8f(const float* __restrict__ p) {
    bf16x8 r;
#pragma unroll
    for (int j = 0; j < 8; j++) r[j] = (short)f2bf_fast(p[j]);
    return r;
}
__device__ __forceinline__ bf16x8 pack8(f32x4 a, f32x4 b) {
    bf16x8 r;
#pragma unroll
    for (int j = 0; j < 4; j++) { r[j] = (short)f2bf_fast(a[j]); r[4 + j] = (short)f2bf_fast(b[j]); }
    return r;
}
// async global->LDS, 16B per lane. LDS dest = wave-uniform base + lane*16.
__device__ __forceinline__ void gl_lds16(const ushort_t* g, ushort_t* l) {
    __builtin_amdgcn_global_load_lds(
        (const __attribute__((address_space(1))) void*)g,
        (__attribute__((address_space(3))) void*)l,
        16, 0, 0);
}

// ---------------------------------------------------------------------------
// fp32->bf16 bulk convert: X (2048 blocks) + Wq/Wk/Wv (512 each). 3584 blocks.
// Outputs live in d_out scratch (dead before oproj overwrites d_out).
// ---------------------------------------------------------------------------
__global__ __launch_bounds__(256)
void cvtall_kernel(const float* __restrict__ X,  const float* __restrict__ Wq,
                   const float* __restrict__ Wk, const float* __restrict__ Wv,
                   ushort_t* __restrict__ Xb,  ushort_t* __restrict__ Wqb,
                   ushort_t* __restrict__ Wkb, ushort_t* __restrict__ Wvb)
{
    int b = blockIdx.x;
    const float* src; ushort_t* dst; size_t off;
    if (b < 2048)      { src = X;  dst = Xb;  off = (size_t)b * 2048; }
    else if (b < 2560) { src = Wq; dst = Wqb; off = (size_t)(b - 2048) * 2048; }
    else if (b < 3072) { src = Wk; dst = Wkb; off = (size_t)(b - 2560) * 2048; }
    else               { src = Wv; dst = Wvb; off = (size_t)(b - 3072) * 2048; }
    size_t i = off + (size_t)threadIdx.x * 8;
    *(bf16x8*)(dst + i) = cvt8f(src + i);
}

// ---------------------------------------------------------------------------
// Fused QKV GEMM (verbatim R11, the 252.7-µs config): BK=64 double-buffer,
// 1 barrier/iter, async DMA staging. for W in {Wq,Wk,Wv}: C = X @ W^T.
// grid (24, 32): mode = x>>3 (0:Q->RoPE+scale, 1:K->RoPE, 2:V->transposed),
// nBase = (x&7)*128. 256 thr, 4 waves (2x2), wave tile 64x64, block 128x128.
// XOR-swizzled LDS: row r's 16B chunk c stored at slot c^(r&7).
// ---------------------------------------------------------------------------
__global__ __launch_bounds__(256)
void qkv_kernel(const ushort_t* __restrict__ Xb,
                const ushort_t* __restrict__ Wqb, const ushort_t* __restrict__ Wkb,
                const ushort_t* __restrict__ Wvb,
                ushort_t* __restrict__ Qo, ushort_t* __restrict__ Ko,
                ushort_t* __restrict__ Vto,
                const float* __restrict__ cosF, const float* __restrict__ sinF)
{
    __shared__ __align__(16) ushort_t As[2][128 * 64];
    __shared__ __align__(16) ushort_t Bs[2][128 * 64];

    const int t     = threadIdx.x;
    const int mode  = blockIdx.x >> 3;
    const int mBase = blockIdx.y * 128;
    const int nBase = (blockIdx.x & 7) * 128;
    const int lane  = t & 63;
    const int wid   = t >> 6;
    const int quad  = lane >> 4;
    const int l15   = lane & 15;
    const int sw    = l15 & 7;          // read-side swizzle key
    const int wm    = (wid & 1) * 64;
    const int wn    = (wid >> 1) * 64;

    const ushort_t* Wb = (mode == 0) ? Wqb : (mode == 1) ? Wkb : Wvb;

    int e[4];
    const ushort_t* xS[4];
    const ushort_t* wS[4];
#pragma unroll
    for (int i = 0; i < 4; i++) {
        e[i] = (i * 256 + t) * 8;
        int row = e[i] >> 6;
        int c   = ((e[i] >> 3) & 7) ^ (row & 7);
        xS[i] = Xb + (size_t)(mBase + row) * D_MODEL + c * 8;
        wS[i] = Wb + (size_t)(nBase + row) * D_MODEL + c * 8;
    }

    f32x4 acc[4][4];
#pragma unroll
    for (int i = 0; i < 4; i++)
#pragma unroll
        for (int j = 0; j < 4; j++) acc[i][j] = (f32x4)(0.0f);

    // prologue: stage tile 0 into buffer 0
#pragma unroll
    for (int i = 0; i < 4; i++) {
        gl_lds16(xS[i], &As[0][e[i]]);
        gl_lds16(wS[i], &Bs[0][e[i]]);
        xS[i] += 64; wS[i] += 64;
    }

    for (int kt = 0; kt < 16; kt++) {
        const int cur = kt & 1, nxt = cur ^ 1;
        __syncthreads();   // buf[cur] staged; all prior reads of buf[nxt] done

        if (kt < 15) {
#pragma unroll
            for (int i = 0; i < 4; i++) {
                gl_lds16(xS[i], &As[nxt][e[i]]);
                gl_lds16(wS[i], &Bs[nxt][e[i]]);
                xS[i] += 64; wS[i] += 64;
            }
        }

#pragma unroll
        for (int ks = 0; ks < 2; ks++) {
            bf16x8 a[4], b[4];
            const int cc = ((ks * 4 + quad) ^ sw) * 8;
#pragma unroll
            for (int mt = 0; mt < 4; mt++)
                a[mt] = *(const bf16x8*)(&As[cur][((wm + mt * 16 + l15) << 6) + cc]);
#pragma unroll
            for (int nt = 0; nt < 4; nt++)
                b[nt] = *(const bf16x8*)(&Bs[cur][((wn + nt * 16 + l15) << 6) + cc]);
#pragma unroll
            for (int mt = 0; mt < 4; mt++)
#pragma unroll
                for (int nt = 0; nt < 4; nt++)
                    acc[mt][nt] = __builtin_amdgcn_mfma_f32_16x16x32_bf16(a[mt], b[nt], acc[mt][nt], 0, 0, 0);
        }
    }

    // Epilogue (verified). C/D: col = l15 (+nt*16), row = quad*4+r (+mt*16).
    if (mode == 2) {
#pragma unroll
        for (int mt = 0; mt < 4; mt++) {
            int m0 = mBase + wm + mt * 16 + quad * 4;
#pragma unroll
            for (int nt = 0; nt < 4; nt++) {
                int n = nBase + wn + nt * 16 + l15;
                u16x4 pk;
#pragma unroll
                for (int r = 0; r < 4; r++) pk[r] = f2bf(acc[mt][nt][r]);
                *(u16x4*)(&Vto[(size_t)n * S_LEN + m0]) = pk;
            }
        }
    } else {
        ushort_t* outB = (mode == 0) ? Qo : Ko;
        const float sc = (mode == 0) ? (0.125f * LOG2E) : 1.0f;
        const int hcb = nBase + wn;
#pragma unroll
        for (int nt = 0; nt < 2; nt++) {
            int f = nt * 16 + l15;   // freq index 0..31
#pragma unroll
            for (int mt = 0; mt < 4; mt++) {
                int m0 = mBase + wm + mt * 16 + quad * 4;
#pragma unroll
                for (int r = 0; r < 4; r++) {
                    int srow = m0 + r;
                    float c = cosF[srow * 32 + f];
                    float s = sinF[srow * 32 + f];
                    float x1 = acc[mt][nt][r];
                    float x2 = acc[mt][nt + 2][r];
                    outB[(size_t)srow * D_MODEL + hcb + f]      = f2bf((x1 * c - x2 * s) * sc);
                    outB[(size_t)srow * D_MODEL + hcb + 32 + f] = f2bf((x2 * c + x1 * s) * sc);
                }
            }
        }
    }
}

// ---------------------------------------------------------------------------
// O projection (verbatim R11, verified): out = Ab @ Wo^T fp32. Tile 64x128,
// A-side async DMA dbuf; B-side W(k+1) fp32 reg-prefetch + cvt into alternate
// buffer after the MFMAs. 1 barrier/iter. grid (8,64)=512 blocks.
// ---------------------------------------------------------------------------
__global__ __launch_bounds__(256)
void oproj_kernel(const ushort_t* __restrict__ Ab, const float* __restrict__ Wf,
                  float* __restrict__ outF)
{
    __shared__ __align__(16) ushort_t As[2][64 * 64];
    __shared__ __align__(16) ushort_t Bs[2][128 * 64];

    const int t     = threadIdx.x;
    const int mBase = blockIdx.y * 64;
    const int nBase = blockIdx.x * 128;
    const int lane  = t & 63;
    const int wid   = t >> 6;
    const int quad  = lane >> 4;
    const int l15   = lane & 15;
    const int sw    = l15 & 7;
    const int wm    = (wid & 1) * 32;
    const int wn    = (wid >> 1) * 64;

    int eA[2], eB[4];
    const ushort_t* aS[2];
    const float*    wS[4];
#pragma unroll
    for (int i = 0; i < 2; i++) {
        eA[i] = (i * 256 + t) * 8;
        int row = eA[i] >> 6;
        int c   = ((eA[i] >> 3) & 7) ^ (row & 7);
        aS[i] = Ab + (size_t)(mBase + row) * D_MODEL + c * 8;
    }
#pragma unroll
    for (int i = 0; i < 4; i++) {
        eB[i] = (i * 256 + t) * 8;
        int row = eB[i] >> 6;
        int c   = ((eB[i] >> 3) & 7) ^ (row & 7);
        wS[i] = Wf + (size_t)(nBase + row) * D_MODEL + c * 8;
    }

    f32x4 acc[2][4];
#pragma unroll
    for (int i = 0; i < 2; i++)
#pragma unroll
        for (int j = 0; j < 4; j++) acc[i][j] = (f32x4)(0.0f);

#pragma unroll
    for (int i = 0; i < 2; i++) { gl_lds16(aS[i], &As[0][eA[i]]); aS[i] += 64; }
#pragma unroll
    for (int i = 0; i < 4; i++) {
        f32x4 w0 = *(const f32x4*)(wS[i]);
        f32x4 w1 = *(const f32x4*)(wS[i] + 4);
        *(bf16x8*)(&Bs[0][eB[i]]) = pack8(w0, w1);
        wS[i] += 64;
    }

    for (int kt = 0; kt < 16; kt++) {
        const int cur = kt & 1, nxt = cur ^ 1;
        __syncthreads();

        f32x4 wr[4][2];
        if (kt < 15) {
#pragma unroll
            for (int i = 0; i < 2; i++) { gl_lds16(aS[i], &As[nxt][eA[i]]); aS[i] += 64; }
#pragma unroll
            for (int i = 0; i < 4; i++) {
                wr[i][0] = *(const f32x4*)(wS[i]);
                wr[i][1] = *(const f32x4*)(wS[i] + 4);
                wS[i] += 64;
            }
        }

#pragma unroll
        for (int ks = 0; ks < 2; ks++) {
            bf16x8 a[2], b[4];
            const int cc = ((ks * 4 + quad) ^ sw) * 8;
#pragma unroll
            for (int mt = 0; mt < 2; mt++)
                a[mt] = *(const bf16x8*)(&As[cur][((wm + mt * 16 + l15) << 6) + cc]);
#pragma unroll
            for (int nt = 0; nt < 4; nt++)
                b[nt] = *(const bf16x8*)(&Bs[cur][((wn + nt * 16 + l15) << 6) + cc]);
#pragma unroll
            for (int mt = 0; mt < 2; mt++)
#pragma unroll
                for (int nt = 0; nt < 4; nt++)
                    acc[mt][nt] = __builtin_amdgcn_mfma_f32_16x16x32_bf16(a[mt], b[nt], acc[mt][nt], 0, 0, 0);
        }

        if (kt < 15) {
#pragma unroll
            for (int i = 0; i < 4; i++)
                *(bf16x8*)(&Bs[nxt][eB[i]]) = pack8(wr[i][0], wr[i][1]);
        }
    }

#pragma unroll
    for (int mt = 0; mt < 2; mt++) {
        int m0 = mBase + wm + mt * 16 + quad * 4;
#pragma unroll
        for (int nt = 0; nt < 4; nt++) {
            int n = nBase + wn + nt * 16 + l15;
#pragma unroll
            for (int r = 0; r < 4; r++)
                outF[(size_t)(m0 + r) * D_MODEL + n] = acc[mt][nt][r];
        }
    }
}

// ---------------------------------------------------------------------------
// Flash attention v6: mt=4 — each wave owns 64 q-rows (BQ=256, 4 waves),
// grid (16,16)=256 blocks = 1/CU. K/V B-fragments now reused 4x per LDS read
// (reads/MFMA 9.9 -> 5.6 cyc). K-tile 64, dbuf staging, 1 barrier/tile,
// Q frags from global, fixed-shift softmax, key-permute at K staging
// (pi(rho)=(rho&15)*4+(rho>>4)) -> contiguous b64 P-stores, V identity
// layout, madd as QK accumulator init. LDS 69.6 KB.
// ---------------------------------------------------------------------------
__global__ __launch_bounds__(256)
void attn_kernel(const ushort_t* __restrict__ Q, const ushort_t* __restrict__ K,
                 const ushort_t* __restrict__ Vt, const float* __restrict__ mask,
                 ushort_t* __restrict__ out)
{
    __shared__ __align__(16) ushort_t Ks[2][64 * 64];
    __shared__ __align__(16) ushort_t Vs[2][64 * 64];
    __shared__ __align__(16) ushort_t Ps[256 * LDP];

    const int t    = threadIdx.x;
    const int h    = blockIdx.y;
    const int qt   = blockIdx.x;
    const int lane = t & 63;
    const int wid  = t >> 6;
    const int quad = lane >> 4;
    const int l15  = lane & 15;
    const int sw   = l15 & 7;
    const int wq   = wid * 64;     // wave's q-row base within the 256-row tile

    // Q fragments straight from global (once per kernel; 8x b128 per lane)
    bf16x8 aq[4][2];
#pragma unroll
    for (int mt = 0; mt < 4; mt++)
#pragma unroll
        for (int ks = 0; ks < 2; ks++)
            aq[mt][ks] = *(const bf16x8*)(&Q[(size_t)(qt * 256 + wq + mt * 16 + l15) * D_MODEL
                                            + h * HEAD_DIM + ks * 32 + quad * 8]);

    // all-ones bf16 B-fragment for the l-sum MFMA
    bf16x8 ones;
#pragma unroll
    for (int j = 0; j < 8; j++) ones[j] = (short)0x3F80;

    // staging source pointers (swizzled chunks); K rows pi-permuted at source
    const int e0 = t * 8,   e1 = (256 + t) * 8;
    const int r0 = e0 >> 6, r1 = e1 >> 6;
    const int c0 = ((e0 >> 3) & 7) ^ (r0 & 7);
    const int c1 = ((e1 >> 3) & 7) ^ (r1 & 7);
    const int p0 = ((r0 & 15) << 2) | (r0 >> 4);   // pi(r0)
    const int p1 = ((r1 & 15) << 2) | (r1 >> 4);   // pi(r1)
    const ushort_t* kS0 = K  + (size_t)p0 * D_MODEL + h * HEAD_DIM + c0 * 8;
    const ushort_t* kS1 = K  + (size_t)p1 * D_MODEL + h * HEAD_DIM + c1 * 8;
    const ushort_t* vS0 = Vt + (size_t)(h * HEAD_DIM + r0) * S_LEN + c0 * 8;
    const ushort_t* vS1 = Vt + (size_t)(h * HEAD_DIM + r1) * S_LEN + c1 * 8;
    const float*    mP  = mask + (l15 << 2);

    f32x4 o_acc[4][4];
    f32x4 l_frag[4];
#pragma unroll
    for (int mt = 0; mt < 4; mt++) {
        l_frag[mt] = (f32x4)(0.0f);
#pragma unroll
        for (int nt = 0; nt < 4; nt++) o_acc[mt][nt] = (f32x4)(0.0f);
    }

    // prologue: stage tile 0 into buffer 0
    gl_lds16(kS0, &Ks[0][e0]);
    gl_lds16(kS1, &Ks[0][e1]);
    gl_lds16(vS0, &Vs[0][e0]);
    gl_lds16(vS1, &Vs[0][e1]);
    kS0 += 64 * D_MODEL; kS1 += 64 * D_MODEL; vS0 += 64; vS1 += 64;

    for (int kt = 0; kt < S_LEN / 64; kt++) {
        const int cur = kt & 1, nxt = cur ^ 1;
        __syncthreads();   // buf[cur] staged; all prior reads of buf[nxt] done

        f32x4 mq = *(const f32x4*)(mP);
        mP += 64;

        if (kt < S_LEN / 64 - 1) {
            gl_lds16(kS0, &Ks[nxt][e0]);
            gl_lds16(kS1, &Ks[nxt][e1]);
            gl_lds16(vS0, &Vs[nxt][e0]);
            gl_lds16(vS1, &Vs[nxt][e1]);
        }
        kS0 += 64 * D_MODEL; kS1 += 64 * D_MODEL; vS0 += 64; vS1 += 64;

        // S = Q K^T + madd (accumulator init; log2 units). S col nt*16+l15
        // corresponds to key l15*4+nt -> madd component nt of the vec4.
        f32x4 sacc[4][4];
        f32x4 mi[4];
#pragma unroll
        for (int nt = 0; nt < 4; nt++)
            mi[nt] = (f32x4)(fmaf(mq[nt], 14426.9504f, -14446.9504f));
#pragma unroll
        for (int mt = 0; mt < 4; mt++)
#pragma unroll
            for (int nt = 0; nt < 4; nt++)
                sacc[mt][nt] = mi[nt];
#pragma unroll
        for (int ks = 0; ks < 2; ks++) {
            bf16x8 bk[4];
            const int cc = ((ks * 4 + quad) ^ sw) * 8;
#pragma unroll
            for (int nt = 0; nt < 4; nt++)
                bk[nt] = *(const bf16x8*)(&Ks[cur][((nt * 16 + l15) << 6) + cc]);
#pragma unroll
            for (int mt = 0; mt < 4; mt++)
#pragma unroll
                for (int nt = 0; nt < 4; nt++)
                    sacc[mt][nt] = __builtin_amdgcn_mfma_f32_16x16x32_bf16(aq[mt][ks], bk[nt], sacc[mt][nt], 0, 0, 0);
        }

        // p = 2^s; pack 4 key-contiguous values -> one b64 store per (mt,r)
#pragma unroll
        for (int mt = 0; mt < 4; mt++) {
            ushort_t* psw = &Ps[(wq + mt * 16 + quad * 4) * LDP + (l15 << 2)];
#pragma unroll
            for (int r = 0; r < 4; r++) {
                u16x4 pk;
                pk[0] = f2bf_fast(ex2(sacc[mt][0][r]));
                pk[1] = f2bf_fast(ex2(sacc[mt][1][r]));
                pk[2] = f2bf_fast(ex2(sacc[mt][2][r]));
                pk[3] = f2bf_fast(ex2(sacc[mt][3][r]));
                *(u16x4*)(&psw[r * LDP]) = pk;
            }
        }
        // NO barrier: Ps rows [wq, wq+64) written and read by this wave only.

        // O += P V ; l += P . 1   (Ps cols and Vs cols are both natural keys)
#pragma unroll
        for (int ks = 0; ks < 2; ks++) {
            bf16x8 ap[4], bv[4];
#pragma unroll
            for (int mt = 0; mt < 4; mt++)
                ap[mt] = *(const bf16x8*)(&Ps[(wq + mt * 16 + l15) * LDP + ks * 32 + quad * 8]);
            const int cc = ((ks * 4 + quad) ^ sw) * 8;
#pragma unroll
            for (int nt = 0; nt < 4; nt++)
                bv[nt] = *(const bf16x8*)(&Vs[cur][((nt * 16 + l15) << 6) + cc]);
#pragma unroll
            for (int mt = 0; mt < 4; mt++) {
#pragma unroll
                for (int nt = 0; nt < 4; nt++)
                    o_acc[mt][nt] = __builtin_amdgcn_mfma_f32_16x16x32_bf16(ap[mt], bv[nt], o_acc[mt][nt], 0, 0, 0);
                l_frag[mt] = __builtin_amdgcn_mfma_f32_16x16x32_bf16(ap[mt], ones, l_frag[mt], 0, 0, 0);
            }
        }
    }

    // normalize + write [s][h*64+hd] (bf16 workspace)
#pragma unroll
    for (int mt = 0; mt < 4; mt++) {
#pragma unroll
        for (int r = 0; r < 4; r++) {
            float inv = 1.0f / fmaxf(l_frag[mt][r], 1e-30f);
            int srow = qt * 256 + wq + mt * 16 + quad * 4 + r;
#pragma unroll
            for (int nt = 0; nt < 4; nt++) {
                int col = h * HEAD_DIM + nt * 16 + l15;
                out[(size_t)srow * D_MODEL + col] = f2bf(o_acc[mt][nt][r] * inv);
            }
        }
    }
}

// ---------------------------------------------------------------------------
extern "C" void kernel_launch(void* const* d_in, const int* in_sizes, int n_in,
                              void* d_out, int out_size, void* d_ws, size_t ws_size,
                              hipStream_t stream)
{
    (void)in_sizes; (void)n_in; (void)out_size; (void)ws_size;

    const float* X    = (const float*)d_in[0];  // [4096][1024]
    const float* cosF = (const float*)d_in[1];  // [4096][32]
    const float* sinF = (const float*)d_in[2];  // [4096][32]
    const float* mask = (const float*)d_in[3];  // [4096]
    const float* Wq   = (const float*)d_in[4];  // [1024][1024]
    const float* Wk   = (const float*)d_in[5];
    const float* Wv   = (const float*)d_in[6];
    const float* Wo   = (const float*)d_in[7];

    const size_t SD = (size_t)S_LEN * D_MODEL;   // 4M elems
    const size_t WD = (size_t)D_MODEL * D_MODEL; // 1M elems

    // ws (>=32MB, proven): Qb | Kb | Vtb | Ab, bf16
    ushort_t* ws  = (ushort_t*)d_ws;
    ushort_t* Qb  = ws;
    ushort_t* Kb  = ws + SD;
    ushort_t* Vtb = ws + 2 * SD;   // [1024][4096], identity key order
    ushort_t* Ab  = ws + 3 * SD;

    // d_out (16MB) doubles as scratch until oproj overwrites every element:
    // Xb (8MB) | Wqb | Wkb | Wvb (2MB each) = 14MB. All dead before oproj.
    float*    outF = (float*)d_out;
    ushort_t* ob   = (ushort_t*)d_out;
    ushort_t* Xb   = ob;
    ushort_t* Wqb  = Xb + SD;
    ushort_t* Wkb  = Wqb + WD;
    ushort_t* Wvb  = Wkb + WD;

    dim3 gQKV(24, 32), gO(8, 64), gA(S_LEN / 256, N_HEADS), bb(256);

    cvtall_kernel<<<3584, bb, 0, stream>>>(X, Wq, Wk, Wv, Xb, Wqb, Wkb, Wvb);
    qkv_kernel<<<gQKV, bb, 0, stream>>>(Xb, Wqb, Wkb, Wvb, Qb, Kb, Vtb, cosF, sinF);
    attn_kernel<<<gA, bb, 0, stream>>>(Qb, Kb, Vtb, mask, Ab);
    oproj_kernel<<<gO, bb, 0, stream>>>(Ab, Wo, outF);
}

// Round 15
// 251.295 us; speedup vs baseline: 1.1394x; 1.1394x over previous
//
#include <hip/hip_runtime.h>
#include <stdint.h>

#define S_LEN   4096
#define D_MODEL 1024
#define N_HEADS 16
#define HEAD_DIM 64
#define LDP 72          // padded stride for Ps only (ds_write path, padding legal)

typedef __attribute__((ext_vector_type(8))) short bf16x8;   // 8 bf16 in 4 VGPRs
typedef __attribute__((ext_vector_type(4))) float f32x4;
typedef __attribute__((ext_vector_type(4))) unsigned short u16x4;
typedef unsigned short ushort_t;

#define LOG2E 1.44269504088896340736f
// Fixed softmax shift: scores in log2 units are ~N(0,1.44); shift of 20 gives
// huge margin and cancels exactly in sum(p*v)/sum(p).
// madd fold: (1-m)*(-10000*log2e) - 20 = fmaf(m, 14426.9504, -14446.9504)

__device__ __forceinline__ ushort_t f2bf(float f) {          // RNE (epilogues)
    union { float f; uint32_t u; } v; v.f = f;
    uint32_t u = v.u;
    return (ushort_t)((u + 0x7fffu + ((u >> 16) & 1u)) >> 16);
}
__device__ __forceinline__ ushort_t f2bf_fast(float f) {     // round-half-up
    union { float f; uint32_t u; } v; v.f = f;
    return (ushort_t)((v.u + 0x8000u) >> 16);
}
__device__ __forceinline__ float ex2(float x) {
#if __has_builtin(__builtin_amdgcn_exp2f)
    return __builtin_amdgcn_exp2f(x);   // single v_exp_f32
#else
    return exp2f(x);
#endif
}
__device__ __forceinline__ bf16x8 cvt8f(const float* __restrict__ p) {
    bf16x8 r;
#pragma unroll
    for (int j = 0; j < 8; j++) r[j] = (short)f2bf_fast(p[j]);
    return r;
}
__device__ __forceinline__ bf16x8 pack8(f32x4 a, f32x4 b) {
    bf16x8 r;
#pragma unroll
    for (int j = 0; j < 4; j++) { r[j] = (short)f2bf_fast(a[j]); r[4 + j] = (short)f2bf_fast(b[j]); }
    return r;
}
// async global->LDS, 16B per lane. LDS dest = wave-uniform base + lane*16.
__device__ __forceinline__ void gl_lds16(const ushort_t* g, ushort_t* l) {
    __builtin_amdgcn_global_load_lds(
        (const __attribute__((address_space(1))) void*)g,
        (__attribute__((address_space(3))) void*)l,
        16, 0, 0);
}

// ---------------------------------------------------------------------------
// fp32->bf16 bulk convert: X (2048 blocks) + Wq/Wk/Wv (512 each). 3584 blocks.
// Outputs live in d_out scratch (dead before oproj overwrites d_out).
// ---------------------------------------------------------------------------
__global__ __launch_bounds__(256)
void cvtall_kernel(const float* __restrict__ X,  const float* __restrict__ Wq,
                   const float* __restrict__ Wk, const float* __restrict__ Wv,
                   ushort_t* __restrict__ Xb,  ushort_t* __restrict__ Wqb,
                   ushort_t* __restrict__ Wkb, ushort_t* __restrict__ Wvb)
{
    int b = blockIdx.x;
    const float* src; ushort_t* dst; size_t off;
    if (b < 2048)      { src = X;  dst = Xb;  off = (size_t)b * 2048; }
    else if (b < 2560) { src = Wq; dst = Wqb; off = (size_t)(b - 2048) * 2048; }
    else if (b < 3072) { src = Wk; dst = Wkb; off = (size_t)(b - 2560) * 2048; }
    else               { src = Wv; dst = Wvb; off = (size_t)(b - 3072) * 2048; }
    size_t i = off + (size_t)threadIdx.x * 8;
    *(bf16x8*)(dst + i) = cvt8f(src + i);
}

// ---------------------------------------------------------------------------
// Fused QKV GEMM (R11 config, measured 252.7 µs total): BK=64 double-buffer,
// 1 barrier/iter, async DMA staging. for W in {Wq,Wk,Wv}: C = X @ W^T.
// grid (24, 32): mode = x>>3 (0:Q->RoPE+scale, 1:K->RoPE, 2:V->transposed),
// nBase = (x&7)*128. 256 thr, 4 waves (2x2), wave tile 64x64, block 128x128.
// XOR-swizzled LDS: row r's 16B chunk c stored at slot c^(r&7).
// ---------------------------------------------------------------------------
__global__ __launch_bounds__(256)
void qkv_kernel(const ushort_t* __restrict__ Xb,
                const ushort_t* __restrict__ Wqb, const ushort_t* __restrict__ Wkb,
                const ushort_t* __restrict__ Wvb,
                ushort_t* __restrict__ Qo, ushort_t* __restrict__ Ko,
                ushort_t* __restrict__ Vto,
                const float* __restrict__ cosF, const float* __restrict__ sinF)
{
    __shared__ __align__(16) ushort_t As[2][128 * 64];
    __shared__ __align__(16) ushort_t Bs[2][128 * 64];

    const int t     = threadIdx.x;
    const int mode  = blockIdx.x >> 3;
    const int mBase = blockIdx.y * 128;
    const int nBase = (blockIdx.x & 7) * 128;
    const int lane  = t & 63;
    const int wid   = t >> 6;
    const int quad  = lane >> 4;
    const int l15   = lane & 15;
    const int sw    = l15 & 7;          // read-side swizzle key
    const int wm    = (wid & 1) * 64;
    const int wn    = (wid >> 1) * 64;

    const ushort_t* Wb = (mode == 0) ? Wqb : (mode == 1) ? Wkb : Wvb;

    int e[4];
    const ushort_t* xS[4];
    const ushort_t* wS[4];
#pragma unroll
    for (int i = 0; i < 4; i++) {
        e[i] = (i * 256 + t) * 8;
        int row = e[i] >> 6;
        int c   = ((e[i] >> 3) & 7) ^ (row & 7);
        xS[i] = Xb + (size_t)(mBase + row) * D_MODEL + c * 8;
        wS[i] = Wb + (size_t)(nBase + row) * D_MODEL + c * 8;
    }

    f32x4 acc[4][4];
#pragma unroll
    for (int i = 0; i < 4; i++)
#pragma unroll
        for (int j = 0; j < 4; j++) acc[i][j] = (f32x4)(0.0f);

    // prologue: stage tile 0 into buffer 0
#pragma unroll
    for (int i = 0; i < 4; i++) {
        gl_lds16(xS[i], &As[0][e[i]]);
        gl_lds16(wS[i], &Bs[0][e[i]]);
        xS[i] += 64; wS[i] += 64;
    }

    for (int kt = 0; kt < 16; kt++) {
        const int cur = kt & 1, nxt = cur ^ 1;
        __syncthreads();   // buf[cur] staged; all prior reads of buf[nxt] done

        if (kt < 15) {
#pragma unroll
            for (int i = 0; i < 4; i++) {
                gl_lds16(xS[i], &As[nxt][e[i]]);
                gl_lds16(wS[i], &Bs[nxt][e[i]]);
                xS[i] += 64; wS[i] += 64;
            }
        }

#pragma unroll
        for (int ks = 0; ks < 2; ks++) {
            bf16x8 a[4], b[4];
            const int cc = ((ks * 4 + quad) ^ sw) * 8;
#pragma unroll
            for (int mt = 0; mt < 4; mt++)
                a[mt] = *(const bf16x8*)(&As[cur][((wm + mt * 16 + l15) << 6) + cc]);
#pragma unroll
            for (int nt = 0; nt < 4; nt++)
                b[nt] = *(const bf16x8*)(&Bs[cur][((wn + nt * 16 + l15) << 6) + cc]);
#pragma unroll
            for (int mt = 0; mt < 4; mt++)
#pragma unroll
                for (int nt = 0; nt < 4; nt++)
                    acc[mt][nt] = __builtin_amdgcn_mfma_f32_16x16x32_bf16(a[mt], b[nt], acc[mt][nt], 0, 0, 0);
        }
    }

    // Epilogue (verified). C/D: col = l15 (+nt*16), row = quad*4+r (+mt*16).
    if (mode == 2) {
#pragma unroll
        for (int mt = 0; mt < 4; mt++) {
            int m0 = mBase + wm + mt * 16 + quad * 4;
#pragma unroll
            for (int nt = 0; nt < 4; nt++) {
                int n = nBase + wn + nt * 16 + l15;
                u16x4 pk;
#pragma unroll
                for (int r = 0; r < 4; r++) pk[r] = f2bf(acc[mt][nt][r]);
                *(u16x4*)(&Vto[(size_t)n * S_LEN + m0]) = pk;
            }
        }
    } else {
        ushort_t* outB = (mode == 0) ? Qo : Ko;
        const float sc = (mode == 0) ? (0.125f * LOG2E) : 1.0f;
        const int hcb = nBase + wn;
#pragma unroll
        for (int nt = 0; nt < 2; nt++) {
            int f = nt * 16 + l15;   // freq index 0..31
#pragma unroll
            for (int mt = 0; mt < 4; mt++) {
                int m0 = mBase + wm + mt * 16 + quad * 4;
#pragma unroll
                for (int r = 0; r < 4; r++) {
                    int srow = m0 + r;
                    float c = cosF[srow * 32 + f];
                    float s = sinF[srow * 32 + f];
                    float x1 = acc[mt][nt][r];
                    float x2 = acc[mt][nt + 2][r];
                    outB[(size_t)srow * D_MODEL + hcb + f]      = f2bf((x1 * c - x2 * s) * sc);
                    outB[(size_t)srow * D_MODEL + hcb + 32 + f] = f2bf((x2 * c + x1 * s) * sc);
                }
            }
        }
    }
}

// ---------------------------------------------------------------------------
// O projection (R11, verified): out = Ab @ Wo^T fp32. Tile 64x128, A-side
// async DMA dbuf; B-side W(k+1) fp32 reg-prefetch + cvt into alternate buffer
// after the MFMAs. 1 barrier/iter. grid (8,64)=512 blocks.
// ---------------------------------------------------------------------------
__global__ __launch_bounds__(256)
void oproj_kernel(const ushort_t* __restrict__ Ab, const float* __restrict__ Wf,
                  float* __restrict__ outF)
{
    __shared__ __align__(16) ushort_t As[2][64 * 64];
    __shared__ __align__(16) ushort_t Bs[2][128 * 64];

    const int t     = threadIdx.x;
    const int mBase = blockIdx.y * 64;
    const int nBase = blockIdx.x * 128;
    const int lane  = t & 63;
    const int wid   = t >> 6;
    const int quad  = lane >> 4;
    const int l15   = lane & 15;
    const int sw    = l15 & 7;
    const int wm    = (wid & 1) * 32;
    const int wn    = (wid >> 1) * 64;

    int eA[2], eB[4];
    const ushort_t* aS[2];
    const float*    wS[4];
#pragma unroll
    for (int i = 0; i < 2; i++) {
        eA[i] = (i * 256 + t) * 8;
        int row = eA[i] >> 6;
        int c   = ((eA[i] >> 3) & 7) ^ (row & 7);
        aS[i] = Ab + (size_t)(mBase + row) * D_MODEL + c * 8;
    }
#pragma unroll
    for (int i = 0; i < 4; i++) {
        eB[i] = (i * 256 + t) * 8;
        int row = eB[i] >> 6;
        int c   = ((eB[i] >> 3) & 7) ^ (row & 7);
        wS[i] = Wf + (size_t)(nBase + row) * D_MODEL + c * 8;
    }

    f32x4 acc[2][4];
#pragma unroll
    for (int i = 0; i < 2; i++)
#pragma unroll
        for (int j = 0; j < 4; j++) acc[i][j] = (f32x4)(0.0f);

#pragma unroll
    for (int i = 0; i < 2; i++) { gl_lds16(aS[i], &As[0][eA[i]]); aS[i] += 64; }
#pragma unroll
    for (int i = 0; i < 4; i++) {
        f32x4 w0 = *(const f32x4*)(wS[i]);
        f32x4 w1 = *(const f32x4*)(wS[i] + 4);
        *(bf16x8*)(&Bs[0][eB[i]]) = pack8(w0, w1);
        wS[i] += 64;
    }

    for (int kt = 0; kt < 16; kt++) {
        const int cur = kt & 1, nxt = cur ^ 1;
        __syncthreads();

        f32x4 wr[4][2];
        if (kt < 15) {
#pragma unroll
            for (int i = 0; i < 2; i++) { gl_lds16(aS[i], &As[nxt][eA[i]]); aS[i] += 64; }
#pragma unroll
            for (int i = 0; i < 4; i++) {
                wr[i][0] = *(const f32x4*)(wS[i]);
                wr[i][1] = *(const f32x4*)(wS[i] + 4);
                wS[i] += 64;
            }
        }

#pragma unroll
        for (int ks = 0; ks < 2; ks++) {
            bf16x8 a[2], b[4];
            const int cc = ((ks * 4 + quad) ^ sw) * 8;
#pragma unroll
            for (int mt = 0; mt < 2; mt++)
                a[mt] = *(const bf16x8*)(&As[cur][((wm + mt * 16 + l15) << 6) + cc]);
#pragma unroll
            for (int nt = 0; nt < 4; nt++)
                b[nt] = *(const bf16x8*)(&Bs[cur][((wn + nt * 16 + l15) << 6) + cc]);
#pragma unroll
            for (int mt = 0; mt < 2; mt++)
#pragma unroll
                for (int nt = 0; nt < 4; nt++)
                    acc[mt][nt] = __builtin_amdgcn_mfma_f32_16x16x32_bf16(a[mt], b[nt], acc[mt][nt], 0, 0, 0);
        }

        if (kt < 15) {
#pragma unroll
            for (int i = 0; i < 4; i++)
                *(bf16x8*)(&Bs[nxt][eB[i]]) = pack8(wr[i][0], wr[i][1]);
        }
    }

#pragma unroll
    for (int mt = 0; mt < 2; mt++) {
        int m0 = mBase + wm + mt * 16 + quad * 4;
#pragma unroll
        for (int nt = 0; nt < 4; nt++) {
            int n = nBase + wn + nt * 16 + l15;
#pragma unroll
            for (int r = 0; r < 4; r++)
                outF[(size_t)(m0 + r) * D_MODEL + n] = acc[mt][nt][r];
        }
    }
}

// ---------------------------------------------------------------------------
// Flash attention v5 (R11, verified): BQ=128 (4 waves x 32 q-rows), K-tile 64,
// dbuf K/V, 1 barrier/tile, Q frags from global, fixed-shift softmax,
// key-permute at K staging (pi(rho)=(rho&15)*4+(rho>>4)) -> contiguous b64
// P-stores, V identity layout, madd as QK accumulator init from one float4
// mask load. grid (32,16)=512 blocks. LDS 50.4 KB.
// ---------------------------------------------------------------------------
__global__ __launch_bounds__(256)
void attn_kernel(const ushort_t* __restrict__ Q, const ushort_t* __restrict__ K,
                 const ushort_t* __restrict__ Vt, const float* __restrict__ mask,
                 ushort_t* __restrict__ out)
{
    __shared__ __align__(16) ushort_t Ks[2][64 * 64];
    __shared__ __align__(16) ushort_t Vs[2][64 * 64];
    __shared__ __align__(16) ushort_t Ps[128 * LDP];

    const int t    = threadIdx.x;
    const int h    = blockIdx.y;
    const int qt   = blockIdx.x;
    const int lane = t & 63;
    const int wid  = t >> 6;
    const int quad = lane >> 4;
    const int l15  = lane & 15;
    const int sw   = l15 & 7;
    const int wq   = wid * 32;

    bf16x8 aq[2][2];
#pragma unroll
    for (int mt = 0; mt < 2; mt++)
#pragma unroll
        for (int ks = 0; ks < 2; ks++)
            aq[mt][ks] = *(const bf16x8*)(&Q[(size_t)(qt * 128 + wq + mt * 16 + l15) * D_MODEL
                                            + h * HEAD_DIM + ks * 32 + quad * 8]);

    bf16x8 ones;
#pragma unroll
    for (int j = 0; j < 8; j++) ones[j] = (short)0x3F80;

    const int e0 = t * 8,   e1 = (256 + t) * 8;
    const int r0 = e0 >> 6, r1 = e1 >> 6;
    const int c0 = ((e0 >> 3) & 7) ^ (r0 & 7);
    const int c1 = ((e1 >> 3) & 7) ^ (r1 & 7);
    const int p0 = ((r0 & 15) << 2) | (r0 >> 4);   // pi(r0)
    const int p1 = ((r1 & 15) << 2) | (r1 >> 4);   // pi(r1)
    const ushort_t* kS0 = K  + (size_t)p0 * D_MODEL + h * HEAD_DIM + c0 * 8;
    const ushort_t* kS1 = K  + (size_t)p1 * D_MODEL + h * HEAD_DIM + c1 * 8;
    const ushort_t* vS0 = Vt + (size_t)(h * HEAD_DIM + r0) * S_LEN + c0 * 8;
    const ushort_t* vS1 = Vt + (size_t)(h * HEAD_DIM + r1) * S_LEN + c1 * 8;
    const float*    mP  = mask + (l15 << 2);

    ushort_t* psw0 = &Ps[(wq + quad * 4) * LDP + (l15 << 2)];
    ushort_t* psw1 = &Ps[(wq + 16 + quad * 4) * LDP + (l15 << 2)];

    f32x4 o_acc[2][4];
    f32x4 l_frag[2];
#pragma unroll
    for (int mt = 0; mt < 2; mt++) {
        l_frag[mt] = (f32x4)(0.0f);
#pragma unroll
        for (int nt = 0; nt < 4; nt++) o_acc[mt][nt] = (f32x4)(0.0f);
    }

    gl_lds16(kS0, &Ks[0][e0]);
    gl_lds16(kS1, &Ks[0][e1]);
    gl_lds16(vS0, &Vs[0][e0]);
    gl_lds16(vS1, &Vs[0][e1]);
    kS0 += 64 * D_MODEL; kS1 += 64 * D_MODEL; vS0 += 64; vS1 += 64;

    for (int kt = 0; kt < S_LEN / 64; kt++) {
        const int cur = kt & 1, nxt = cur ^ 1;
        __syncthreads();

        f32x4 mq = *(const f32x4*)(mP);
        mP += 64;

        if (kt < S_LEN / 64 - 1) {
            gl_lds16(kS0, &Ks[nxt][e0]);
            gl_lds16(kS1, &Ks[nxt][e1]);
            gl_lds16(vS0, &Vs[nxt][e0]);
            gl_lds16(vS1, &Vs[nxt][e1]);
        }
        kS0 += 64 * D_MODEL; kS1 += 64 * D_MODEL; vS0 += 64; vS1 += 64;

        f32x4 sacc[2][4];
#pragma unroll
        for (int mt = 0; mt < 2; mt++)
#pragma unroll
            for (int nt = 0; nt < 4; nt++)
                sacc[mt][nt] = (f32x4)(fmaf(mq[nt], 14426.9504f, -14446.9504f));
#pragma unroll
        for (int ks = 0; ks < 2; ks++) {
            bf16x8 bk[4];
            const int cc = ((ks * 4 + quad) ^ sw) * 8;
#pragma unroll
            for (int nt = 0; nt < 4; nt++)
                bk[nt] = *(const bf16x8*)(&Ks[cur][((nt * 16 + l15) << 6) + cc]);
#pragma unroll
            for (int mt = 0; mt < 2; mt++)
#pragma unroll
                for (int nt = 0; nt < 4; nt++)
                    sacc[mt][nt] = __builtin_amdgcn_mfma_f32_16x16x32_bf16(aq[mt][ks], bk[nt], sacc[mt][nt], 0, 0, 0);
        }

        // p = 2^s; pack 4 key-contiguous values -> one b64 store per (mt,r)
#pragma unroll
        for (int mt = 0; mt < 2; mt++) {
            ushort_t* psw = mt ? psw1 : psw0;
#pragma unroll
            for (int r = 0; r < 4; r++) {
                u16x4 pk;
                pk[0] = f2bf_fast(ex2(sacc[mt][0][r]));
                pk[1] = f2bf_fast(ex2(sacc[mt][1][r]));
                pk[2] = f2bf_fast(ex2(sacc[mt][2][r]));
                pk[3] = f2bf_fast(ex2(sacc[mt][3][r]));
                *(u16x4*)(&psw[r * LDP]) = pk;
            }
        }
        // NO barrier: Ps rows [wq, wq+32) written and read by this wave only.

#pragma unroll
        for (int ks = 0; ks < 2; ks++) {
            bf16x8 ap[2], bv[4];
#pragma unroll
            for (int mt = 0; mt < 2; mt++)
                ap[mt] = *(const bf16x8*)(&Ps[(wq + mt * 16 + l15) * LDP + ks * 32 + quad * 8]);
            const int cc = ((ks * 4 + quad) ^ sw) * 8;
#pragma unroll
            for (int nt = 0; nt < 4; nt++)
                bv[nt] = *(const bf16x8*)(&Vs[cur][((nt * 16 + l15) << 6) + cc]);
#pragma unroll
            for (int mt = 0; mt < 2; mt++) {
#pragma unroll
                for (int nt = 0; nt < 4; nt++)
                    o_acc[mt][nt] = __builtin_amdgcn_mfma_f32_16x16x32_bf16(ap[mt], bv[nt], o_acc[mt][nt], 0, 0, 0);
                l_frag[mt] = __builtin_amdgcn_mfma_f32_16x16x32_bf16(ap[mt], ones, l_frag[mt], 0, 0, 0);
            }
        }
    }

#pragma unroll
    for (int mt = 0; mt < 2; mt++) {
#pragma unroll
        for (int r = 0; r < 4; r++) {
            float inv = 1.0f / fmaxf(l_frag[mt][r], 1e-30f);
            int srow = qt * 128 + wq + mt * 16 + quad * 4 + r;
#pragma unroll
            for (int nt = 0; nt < 4; nt++) {
                int col = h * HEAD_DIM + nt * 16 + l15;
                out[(size_t)srow * D_MODEL + col] = f2bf(o_acc[mt][nt][r] * inv);
            }
        }
    }
}

// ---------------------------------------------------------------------------
extern "C" void kernel_launch(void* const* d_in, const int* in_sizes, int n_in,
                              void* d_out, int out_size, void* d_ws, size_t ws_size,
                              hipStream_t stream)
{
    (void)in_sizes; (void)n_in; (void)out_size; (void)ws_size;

    const float* X    = (const float*)d_in[0];  // [4096][1024]
    const float* cosF = (const float*)d_in[1];  // [4096][32]
    const float* sinF = (const float*)d_in[2];  // [4096][32]
    const float* mask = (const float*)d_in[3];  // [4096]
    const float* Wq   = (const float*)d_in[4];  // [1024][1024]
    const float* Wk   = (const float*)d_in[5];
    const float* Wv   = (const float*)d_in[6];
    const float* Wo   = (const float*)d_in[7];

    const size_t SD = (size_t)S_LEN * D_MODEL;   // 4M elems
    const size_t WD = (size_t)D_MODEL * D_MODEL; // 1M elems

    // ws (>=32MB, proven): Qb | Kb | Vtb | Ab, bf16
    ushort_t* ws  = (ushort_t*)d_ws;
    ushort_t* Qb  = ws;
    ushort_t* Kb  = ws + SD;
    ushort_t* Vtb = ws + 2 * SD;   // [1024][4096], identity key order
    ushort_t* Ab  = ws + 3 * SD;

    // d_out (16MB) doubles as scratch until oproj overwrites every element:
    // Xb (8MB) | Wqb | Wkb | Wvb (2MB each) = 14MB. All dead before oproj.
    float*    outF = (float*)d_out;
    ushort_t* ob   = (ushort_t*)d_out;
    ushort_t* Xb   = ob;
    ushort_t* Wqb  = Xb + SD;
    ushort_t* Wkb  = Wqb + WD;
    ushort_t* Wvb  = Wkb + WD;

    dim3 gQKV(24, 32), gO(8, 64), gA(S_LEN / 128, N_HEADS), bb(256);

    cvtall_kernel<<<3584, bb, 0, stream>>>(X, Wq, Wk, Wv, Xb, Wqb, Wkb, Wvb);
    qkv_kernel<<<gQKV, bb, 0, stream>>>(Xb, Wqb, Wkb, Wvb, Qb, Kb, Vtb, cosF, sinF);
    attn_kernel<<<gA, bb, 0, stream>>>(Qb, Kb, Vtb, mask, Ab);
    oproj_kernel<<<gO, bb, 0, stream>>>(Ab, Wo, outF);
}